// Round 8
// baseline (3323.929 us; speedup 1.0000x reference)
//
#include <hip/hip_runtime.h>

#define NP 131072   // points (= 2^17, label packs above bit 17)
#define DD 128      // dims (GEMM K)
#define KK 256      // clusters (GEMM N)
#define MAXIT 8
#define TOLSQ (1e-4f * 1e-4f)
#define POSB 256    // positions per k_sum block
#define UPIPE 8     // gather pipeline depth

typedef _Float16 half8 __attribute__((ext_vector_type(8)));
typedef float f32x4 __attribute__((ext_vector_type(4)));

// Async 16B global -> LDS DMA. ldsptr must be the WAVE-UNIFORM base; HW
// writes base + lane*16 (m97/m104 semantics). Our layouts are exactly
// lane-contiguous in fragment order.
__device__ __forceinline__ void async_copy16(const void* g, void* l) {
    __builtin_amdgcn_global_load_lds(
        (const __attribute__((address_space(1))) void*)g,
        (__attribute__((address_space(3))) void*)l, 16, 0, 0);
}

// ws re-poisoned 0xAA before every timed call — every field below is written
// before it is read on every kernel_launch.
struct Ws {
    float C[KK * DD];
    float newC[KK * DD];
    float cnorm[KK];
    float sums[KK * DD];       // per-cluster coordinate sums (atomic-flushed)
    float shiftsq;
    int done;
    int ilab[NP];              // labels
    int counts[KK];            // per-cluster sizes (exact, int)
    int cursor[KK];            // global reservation cursors (zeroed per iter)
    int ordlab[NP];            // cluster-sorted: point | (label<<17)
    // fp16 hi/lo planes, pre-swizzled into MFMA fragment order (16B aligned)
    alignas(16) _Float16 Csh[KK * DD];
    alignas(16) _Float16 Csl[KK * DD];
    alignas(16) _Float16 Xsh[(size_t)NP * DD];
    alignas(16) _Float16 Xsl[(size_t)NP * DD];
};

// C0 = X[init_idx]; zero done flag.  grid: KK x DD
__global__ void k_init(const float* __restrict__ X, const int* __restrict__ idx,
                       float* __restrict__ C, int* __restrict__ done) {
    int k = blockIdx.x, d = threadIdx.x;
    C[k * DD + d] = X[(size_t)idx[k] * DD + d];
    if (k == 0 && d == 0) *done = 0;
}

// Once per call: split X into fp16 hi/lo planes in A-fragment order.
// A-frag (16x16x32 f16): lane L of the wave owning 16-point group g16 at
// k-step ks holds X[g16*16 + (L&15)][ks*32 + (L>>4)*8 + j], j=0..7.
// Flat: Xs[(((g16*4)+ks)*64 + L)*8 + j].  grid: NP*DD/8/256 = 8192 blocks.
__global__ void k_split(const float* __restrict__ X, _Float16* __restrict__ Xh,
                        _Float16* __restrict__ Xl) {
    size_t idx = (size_t)blockIdx.x * 256 + threadIdx.x;  // one per 8 elems
    int lane = idx & 63;
    size_t g16k = idx >> 6;
    size_t point = (g16k >> 2) * 16 + (lane & 15);
    int dim0 = (int)(g16k & 3) * 32 + (lane >> 4) * 8;
    const f32x4* s4 = (const f32x4*)(X + point * DD + dim0);
    f32x4 a = s4[0], b = s4[1];
    half8 h, l;
#pragma unroll
    for (int j = 0; j < 4; j++) {
        _Float16 hi = (_Float16)a[j];
        h[j] = hi; l[j] = (_Float16)(a[j] - (float)hi);
    }
#pragma unroll
    for (int j = 0; j < 4; j++) {
        _Float16 hi = (_Float16)b[j];
        h[4 + j] = hi; l[4 + j] = (_Float16)(b[j] - (float)hi);
    }
    *(half8*)(Xh + idx * 8) = h;
    *(half8*)(Xl + idx * 8) = l;
}

// Initial prep: cnorm + hi/lo B-fragment planes for C0; zero counts/cursor.
// B-frag: lane L at (ks, cluster-tile ct) holds C[ct*16+(L&15)][ks*32+(L>>4)*8+j]
// -> flat ((ks*16+ct)*64 + L)*8 + j.  grid: KK x DD
__global__ void k_prep0(const float* __restrict__ C, float* __restrict__ cnorm,
                        _Float16* __restrict__ Ch, _Float16* __restrict__ Cl,
                        int* __restrict__ counts, int* __restrict__ cursor) {
    int k = blockIdx.x, d = threadIdx.x;
    float v = C[k * DD + d];
    _Float16 hi = (_Float16)v;
    int ct = k >> 4, l4 = k & 15, ks = d >> 5, q = (d >> 3) & 3, j = d & 7;
    size_t dst = ((size_t)(ks * 16 + ct) * 64 + (q * 16 + l4)) * 8 + j;
    Ch[dst] = hi;
    Cl[dst] = (_Float16)(v - (float)hi);
    __shared__ float red[DD];
    red[d] = v * v;
    __syncthreads();
    for (int s = DD / 2; s > 0; s >>= 1) {
        if (d < s) red[d] += red[d + s];
        __syncthreads();
    }
    if (d == 0) {
        cnorm[k] = red[0];
        counts[k] = 0;
        cursor[k] = 0;
    }
}

// MFMA assignment, LDS-staged B. Per ks-slice (K=32): block DMAs the 32 KB
// Ch/Cl slice into LDS (global_load_lds width=16, lane-contiguous), then each
// wave reads B-frags via ds_read_b128 at IMMEDIATE offsets — B global traffic
// drops 4x (once per block, not per wave) and the inner loop has no 64-bit
// address VALU. A-frags (compulsory 16 KB/wave) hoisted to registers upfront.
// Wave = 32 points x 256 clusters; fp16 hi/lo 3-term split, fp32 acc.
// grid: NP/128 x 256.
__global__ __launch_bounds__(256, 2) void k_assign(
    const _Float16* __restrict__ Xh, const _Float16* __restrict__ Xl,
    const _Float16* __restrict__ Ch, const _Float16* __restrict__ Cl,
    const float* __restrict__ cnorm, float* __restrict__ outlab,
    int* __restrict__ ilab, int* __restrict__ counts,
    float* __restrict__ shiftsq) {
    __shared__ __align__(16) _Float16 Bls[2 * 16 * 64 * 8];  // 32 KB: [plane][ct][lane][8]
    __shared__ int hist[KK];
    if (blockIdx.x == 0 && threadIdx.x == 0) *shiftsq = 0.0f;
    hist[threadIdx.x] = 0;

    const int wave = threadIdx.x >> 6;
    const int lane = threadIdx.x & 63;
    const int l4 = lane & 15, g = lane >> 4;
    const int g16 = blockIdx.x * 8 + wave * 2;

    // Hoist ALL A loads (16 KB/wave, compulsory): 32 dwordx4 in flight.
    half8 Ah[4][2], Al[4][2];
#pragma unroll
    for (int ks = 0; ks < 4; ks++)
#pragma unroll
        for (int pg = 0; pg < 2; pg++) {
            const size_t a = ((size_t)((g16 + pg) * 4 + ks) * 64 + lane) * 8;
            Ah[ks][pg] = *(const half8*)(Xh + a);
            Al[ks][pg] = *(const half8*)(Xl + a);
        }

    f32x4 acc[2][16];
#pragma unroll
    for (int pg = 0; pg < 2; pg++)
#pragma unroll
        for (int ct = 0; ct < 16; ct++) acc[pg][ct] = (f32x4){0.f, 0.f, 0.f, 0.f};

    char* lds0 = (char*)Bls;
#pragma unroll 1
    for (int ks = 0; ks < 4; ks++) {
        __syncthreads();  // previous slice fully consumed before overwrite
        // Stage 16 KB Ch-slice + 16 KB Cl-slice: per wave per j, 64 lanes x 16B.
#pragma unroll
        for (int j = 0; j < 4; j++) {
            const int slot = j * 256 + wave * 64;  // 16B units within plane
            async_copy16(Ch + (size_t)ks * 8192 + (size_t)(slot + lane) * 8,
                         lds0 + (size_t)slot * 16);
            async_copy16(Cl + (size_t)ks * 8192 + (size_t)(slot + lane) * 8,
                         lds0 + 16384 + (size_t)slot * 16);
        }
        __syncthreads();  // vmcnt(0) drain -> staged B visible

#pragma unroll
        for (int ct = 0; ct < 16; ct++) {
            half8 bh = *(const half8*)(lds0 + ct * 1024 + lane * 16);
            half8 bl = *(const half8*)(lds0 + 16384 + ct * 1024 + lane * 16);
            acc[0][ct] = __builtin_amdgcn_mfma_f32_16x16x32_f16(Al[ks][0], bh, acc[0][ct], 0, 0, 0);
            acc[0][ct] = __builtin_amdgcn_mfma_f32_16x16x32_f16(Ah[ks][0], bl, acc[0][ct], 0, 0, 0);
            acc[0][ct] = __builtin_amdgcn_mfma_f32_16x16x32_f16(Ah[ks][0], bh, acc[0][ct], 0, 0, 0);
            acc[1][ct] = __builtin_amdgcn_mfma_f32_16x16x32_f16(Al[ks][1], bh, acc[1][ct], 0, 0, 0);
            acc[1][ct] = __builtin_amdgcn_mfma_f32_16x16x32_f16(Ah[ks][1], bl, acc[1][ct], 0, 0, 0);
            acc[1][ct] = __builtin_amdgcn_mfma_f32_16x16x32_f16(Ah[ks][1], bh, acc[1][ct], 0, 0, 0);
        }
    }

    float cn[16];
#pragma unroll
    for (int ct = 0; ct < 16; ct++) cn[ct] = cnorm[ct * 16 + l4];

    // Packed argmin keys: (monotone(float) << 32) | cluster. NaN -> -inf so
    // NaN beats all finite values; low bits give np's first-index tie-break.
    unsigned long long best[2][4];
#pragma unroll
    for (int pg = 0; pg < 2; pg++)
#pragma unroll
        for (int r = 0; r < 4; r++) best[pg][r] = ~0ull;

#pragma unroll
    for (int pg = 0; pg < 2; pg++)
#pragma unroll
        for (int ct = 0; ct < 16; ct++)
#pragma unroll
            for (int r = 0; r < 4; r++) {
                float s = fmaf(-2.0f, acc[pg][ct][r], cn[ct]);
                if (__builtin_isnan(s)) s = -__builtin_inff();
                unsigned u = __float_as_uint(s);
                unsigned m = (u >> 31) ? ~u : (u ^ 0x80000000u);
                unsigned long long key =
                    ((unsigned long long)m << 32) | (unsigned)(ct * 16 + l4);
                if (key < best[pg][r]) best[pg][r] = key;
            }

    // reduce over the 16 cluster-column lanes (low 4 lane bits)
#pragma unroll
    for (int d = 1; d < 16; d <<= 1)
#pragma unroll
        for (int pg = 0; pg < 2; pg++)
#pragma unroll
            for (int r = 0; r < 4; r++) {
                unsigned long long o = __shfl_xor(best[pg][r], d, 64);
                if (o < best[pg][r]) best[pg][r] = o;
            }

    __syncthreads();  // hist zero visible (also orders vs staging barriers)
    if (l4 == 0) {
#pragma unroll
        for (int pg = 0; pg < 2; pg++)
#pragma unroll
            for (int r = 0; r < 4; r++) {
                int point = blockIdx.x * 128 + wave * 32 + pg * 16 + g * 4 + r;
                int lbl = (int)(best[pg][r] & 0x1ff);
                outlab[point] = (float)lbl;
                ilab[point] = lbl;
                atomicAdd(&hist[lbl], 1);
            }
    }
    __syncthreads();
    int h = hist[threadIdx.x];
    if (h) atomicAdd(&counts[threadIdx.x], h);
}

// Counting-sort scatter. Block = 512 points: LDS histogram, redundant prefix
// of global counts, ONE block-aggregated cursor reservation per cluster, then
// rank & write ordlab[pos] = p | (label<<17). Also zeroes sums for k_sum.
// grid: NP/512 = 256 blocks x 256 threads.
__global__ __launch_bounds__(256) void k_scatter(
    const int* __restrict__ ilab, const int* __restrict__ counts,
    int* __restrict__ cursor, int* __restrict__ ordlab,
    float* __restrict__ sums) {
    const int t = threadIdx.x;
    const int b = blockIdx.x;

    // zero sums slice: 256 blocks x 128 floats = KK*DD
    if (t < 128) sums[b * 128 + t] = 0.0f;

    __shared__ int hist[KK];
    __shared__ int pre[KK];
    __shared__ int gbase[KK];
    hist[t] = 0;
    int c = counts[t];
    pre[t] = c;
    __syncthreads();

    const int p0 = b * 512;
    const int la = ilab[p0 + t];
    const int lb = ilab[p0 + 256 + t];
    atomicAdd(&hist[la], 1);
    atomicAdd(&hist[lb], 1);

    // inclusive prefix of counts (Hillis-Steele)
#pragma unroll
    for (int d = 1; d < KK; d <<= 1) {
        int v = (t >= d) ? pre[t - d] : 0;
        __syncthreads();
        pre[t] += v;
        __syncthreads();
    }
    // after these syncs all hist atomics are complete
    int h = hist[t];
    int gb = (pre[t] - c) + (h ? atomicAdd(&cursor[t], h) : 0);
    gbase[t] = gb;
    __syncthreads();
    hist[t] = 0;  // reuse as intra-block rank cursor
    __syncthreads();

    int ra = atomicAdd(&hist[la], 1);
    ordlab[gbase[la] + ra] = (p0 + t) | (la << 17);
    int rb = atomicAdd(&hist[lb], 1);
    ordlab[gbase[lb] + rb] = (p0 + 256 + t) | (lb << 17);
}

// Streaming segmented sum over the cluster-sorted position list.
// Position-balanced (immune to cluster-size skew). Thread = (dim d, parity h);
// U-deep double-buffered row gathers; register accumulator flushed on label
// change (wave-uniform branch) via coalesced global atomicAdd — few per block.
// grid: NP/POSB = 512 blocks x 256 threads.
__global__ __launch_bounds__(256) void k_sum(
    const float* __restrict__ X, const int* __restrict__ ordlab,
    float* __restrict__ sums) {
    const int t = threadIdx.x;
    const int d = t & 127, h = t >> 7;

    __shared__ int sol[POSB];
    sol[t] = ordlab[blockIdx.x * POSB + t];
    __syncthreads();

    const int PP = POSB / 2;  // positions per parity
    float xv[UPIPE], xn[UPIPE];
#pragma unroll
    for (int u = 0; u < UPIPE; u++)
        xv[u] = X[(size_t)(sol[2 * u + h] & 0x1ffff) * DD + d];

    float acc = 0.0f;
    int cur = sol[h] >> 17;

    for (int jb = 0; jb < PP; jb += UPIPE) {
        // issue next batch's gathers (tail clamped to a harmless valid index)
#pragma unroll
        for (int u = 0; u < UPIPE; u++) {
            int nj = jb + u + UPIPE;
            int o = sol[2 * (nj < PP ? nj : PP - 1) + h];
            xn[u] = X[(size_t)(o & 0x1ffff) * DD + d];
        }
        // consume current batch
#pragma unroll
        for (int u = 0; u < UPIPE; u++) {
            int l = sol[2 * (jb + u) + h] >> 17;
            if (l != cur) {
                atomicAdd(&sums[cur * DD + d], acc);
                acc = 0.0f;
                cur = l;
            }
            acc += xv[u];
        }
#pragma unroll
        for (int u = 0; u < UPIPE; u++) xv[u] = xn[u];
    }
    atomicAdd(&sums[cur * DD + d], acc);
}

// newC = sums/counts (0/0 -> NaN, matching jnp); shift^2 block-reduced,
// one atomic per block.  grid: KK*DD/256 x 256
__global__ void k_reduce(const float* __restrict__ sums, const int* __restrict__ counts,
                         const float* __restrict__ C, float* __restrict__ newC,
                         float* __restrict__ shiftsq) {
    const int g = blockIdx.x * 256 + threadIdx.x;
    const int k = g >> 7;
    const int t = threadIdx.x;

    float nc = sums[g] / (float)counts[k];
    newC[g] = nc;
    float diff = nc - C[g];

    __shared__ float red[256];
    red[t] = diff * diff;
    __syncthreads();
    for (int st = 128; st > 0; st >>= 1) {
        if (t < st) red[t] += red[t + st];
        __syncthreads();
    }
    if (t == 0) atomicAdd(shiftsq, red[0]);
}

// Fused convergence check + centroid update + next-iter prep (cnorm + hi/lo
// planes) + zero counts/cursor. NaN shiftsq -> not converged (jnp match).
// Benign done race: all blocks compute the same nd.  grid: KK/2 x 256.
__global__ void k_upprep(const float* __restrict__ newC, float* __restrict__ C,
                         const float* __restrict__ shiftsq, int* __restrict__ done,
                         float* __restrict__ cnorm, _Float16* __restrict__ Ch,
                         _Float16* __restrict__ Cl, int* __restrict__ counts,
                         int* __restrict__ cursor) {
    const int t = threadIdx.x;
    const int k = blockIdx.x * 2 + (t >> 7);
    const int d = t & 127;
    float ss = *shiftsq;
    int nd = (*done != 0) || (ss < TOLSQ);
    float v = nd ? C[k * DD + d] : newC[k * DD + d];
    C[k * DD + d] = v;
    if (blockIdx.x == 0 && t == 0 && nd) *done = 1;
    if (d == 0) {
        counts[k] = 0;
        cursor[k] = 0;
    }

    _Float16 hi = (_Float16)v;
    int ct = k >> 4, l4 = k & 15, ks = d >> 5, q = (d >> 3) & 3, j = d & 7;
    size_t dst = ((size_t)(ks * 16 + ct) * 64 + (q * 16 + l4)) * 8 + j;
    Ch[dst] = hi;
    Cl[dst] = (_Float16)(v - (float)hi);

    __shared__ float red[256];
    red[t] = v * v;
    __syncthreads();
    for (int s = 64; s > 0; s >>= 1) {
        if ((t & 127) < s) red[t] += red[t + s];
        __syncthreads();
    }
    if (d == 0) cnorm[k] = red[t];
}

__global__ void k_final(const float* __restrict__ C, float* __restrict__ out) {
    int i = blockIdx.x * 256 + threadIdx.x;
    out[i] = C[i];
}

extern "C" void kernel_launch(void* const* d_in, const int* in_sizes, int n_in,
                              void* d_out, int out_size, void* d_ws, size_t ws_size,
                              hipStream_t stream) {
    const float* X = (const float*)d_in[0];
    const int* idx = (const int*)d_in[1];
    float* out = (float*)d_out;
    Ws* w = (Ws*)d_ws;

    k_init<<<KK, DD, 0, stream>>>(X, idx, w->C, &w->done);
    k_split<<<(int)((size_t)NP * DD / 8 / 256), 256, 0, stream>>>(X, w->Xsh, w->Xsl);
    k_prep0<<<KK, DD, 0, stream>>>(w->C, w->cnorm, w->Csh, w->Csl, w->counts, w->cursor);

    for (int it = 0; it < MAXIT; it++) {
        k_assign<<<NP / 128, 256, 0, stream>>>(w->Xsh, w->Xsl, w->Csh, w->Csl,
                                               w->cnorm, out, w->ilab, w->counts,
                                               &w->shiftsq);
        k_scatter<<<NP / 512, 256, 0, stream>>>(w->ilab, w->counts, w->cursor,
                                                w->ordlab, w->sums);
        k_sum<<<NP / POSB, 256, 0, stream>>>(X, w->ordlab, w->sums);
        k_reduce<<<KK * DD / 256, 256, 0, stream>>>(w->sums, w->counts, w->C,
                                                    w->newC, &w->shiftsq);
        k_upprep<<<KK / 2, 256, 0, stream>>>(w->newC, w->C, &w->shiftsq, &w->done,
                                             w->cnorm, w->Csh, w->Csl, w->counts,
                                             w->cursor);
    }

    k_final<<<KK * DD / 256, 256, 0, stream>>>(w->C, out + NP);
}

// Round 9
// 722.447 us; speedup vs baseline: 4.6009x; 4.6009x over previous
//
#include <hip/hip_runtime.h>

#define NP 131072   // points (= 2^17, label packs above bit 17)
#define DD 128      // dims (GEMM K)
#define KK 256      // clusters (GEMM N)
#define MAXIT 8
#define TOLSQ (1e-4f * 1e-4f)
#define POSB 256    // positions per k_sum block
#define UPIPE 8     // gather pipeline depth

typedef _Float16 half8 __attribute__((ext_vector_type(8)));
typedef float f32x4 __attribute__((ext_vector_type(4)));

// Async 16B global -> LDS DMA. ldsptr must be the WAVE-UNIFORM base; HW
// writes base + lane*16 (m97/m104 semantics). Our layouts are exactly
// lane-contiguous in fragment order.
__device__ __forceinline__ void async_copy16(const void* g, void* l) {
    __builtin_amdgcn_global_load_lds(
        (const __attribute__((address_space(1))) void*)g,
        (__attribute__((address_space(3))) void*)l, 16, 0, 0);
}

// ws re-poisoned 0xAA before every timed call — every field below is written
// before it is read on every kernel_launch.
struct Ws {
    float C[KK * DD];
    float newC[KK * DD];
    float cnorm[KK];
    float sums[KK * DD];       // per-cluster coordinate sums (atomic-flushed)
    float shiftsq;
    int done;
    int ilab[NP];              // labels
    int counts[KK];            // per-cluster sizes (exact, int)
    int cursor[KK];            // global reservation cursors (zeroed per iter)
    int ordlab[NP];            // cluster-sorted: point | (label<<17)
    // fp16 hi/lo planes, pre-swizzled into MFMA fragment order (16B aligned)
    alignas(16) _Float16 Csh[KK * DD];
    alignas(16) _Float16 Csl[KK * DD];
    alignas(16) _Float16 Xsh[(size_t)NP * DD];
    alignas(16) _Float16 Xsl[(size_t)NP * DD];
};

// C0 = X[init_idx]; zero done flag.  grid: KK x DD
__global__ void k_init(const float* __restrict__ X, const int* __restrict__ idx,
                       float* __restrict__ C, int* __restrict__ done) {
    int k = blockIdx.x, d = threadIdx.x;
    C[k * DD + d] = X[(size_t)idx[k] * DD + d];
    if (k == 0 && d == 0) *done = 0;
}

// Once per call: split X into fp16 hi/lo planes in A-fragment order.
// A-frag (16x16x32 f16): lane L of the wave owning 16-point group g16 at
// k-step ks holds X[g16*16 + (L&15)][ks*32 + (L>>4)*8 + j], j=0..7.
// Flat: Xs[(((g16*4)+ks)*64 + L)*8 + j].  grid: NP*DD/8/256 = 8192 blocks.
__global__ void k_split(const float* __restrict__ X, _Float16* __restrict__ Xh,
                        _Float16* __restrict__ Xl) {
    size_t idx = (size_t)blockIdx.x * 256 + threadIdx.x;  // one per 8 elems
    int lane = idx & 63;
    size_t g16k = idx >> 6;
    size_t point = (g16k >> 2) * 16 + (lane & 15);
    int dim0 = (int)(g16k & 3) * 32 + (lane >> 4) * 8;
    const f32x4* s4 = (const f32x4*)(X + point * DD + dim0);
    f32x4 a = s4[0], b = s4[1];
    half8 h, l;
#pragma unroll
    for (int j = 0; j < 4; j++) {
        _Float16 hi = (_Float16)a[j];
        h[j] = hi; l[j] = (_Float16)(a[j] - (float)hi);
    }
#pragma unroll
    for (int j = 0; j < 4; j++) {
        _Float16 hi = (_Float16)b[j];
        h[4 + j] = hi; l[4 + j] = (_Float16)(b[j] - (float)hi);
    }
    *(half8*)(Xh + idx * 8) = h;
    *(half8*)(Xl + idx * 8) = l;
}

// Initial prep: cnorm + hi/lo B-fragment planes for C0; zero counts/cursor.
// B-frag: lane L at (ks, cluster-tile ct) holds C[ct*16+(L&15)][ks*32+(L>>4)*8+j]
// -> flat ((ks*16+ct)*64 + L)*8 + j.  grid: KK x DD
__global__ void k_prep0(const float* __restrict__ C, float* __restrict__ cnorm,
                        _Float16* __restrict__ Ch, _Float16* __restrict__ Cl,
                        int* __restrict__ counts, int* __restrict__ cursor) {
    int k = blockIdx.x, d = threadIdx.x;
    float v = C[k * DD + d];
    _Float16 hi = (_Float16)v;
    int ct = k >> 4, l4 = k & 15, ks = d >> 5, q = (d >> 3) & 3, j = d & 7;
    size_t dst = ((size_t)(ks * 16 + ct) * 64 + (q * 16 + l4)) * 8 + j;
    Ch[dst] = hi;
    Cl[dst] = (_Float16)(v - (float)hi);
    __shared__ float red[DD];
    red[d] = v * v;
    __syncthreads();
    for (int s = DD / 2; s > 0; s >>= 1) {
        if (d < s) red[d] += red[d + s];
        __syncthreads();
    }
    if (d == 0) {
        cnorm[k] = red[0];
        counts[k] = 0;
        cursor[k] = 0;
    }
}

// MFMA assignment, LDS-staged B (R8 layout, proven correct) WITHOUT the A-
// hoist that spilled in R8: this ks-slice's A frags (16 VGPRs) are loaded
// inside the loop, issued before the staging barrier so their latency hides
// under the DMA drain. Register plan: acc 128 + A 16 + B 8 + addr ~30 < 256.
// B global traffic: once per block per slice (8x less L2 than R7).
// Wave = 32 points x 256 clusters; fp16 hi/lo 3-term split, fp32 acc.
// grid: NP/128 x 256.
__global__ __launch_bounds__(256, 2) void k_assign(
    const _Float16* __restrict__ Xh, const _Float16* __restrict__ Xl,
    const _Float16* __restrict__ Ch, const _Float16* __restrict__ Cl,
    const float* __restrict__ cnorm, float* __restrict__ outlab,
    int* __restrict__ ilab, int* __restrict__ counts,
    float* __restrict__ shiftsq) {
    __shared__ __align__(16) _Float16 Bls[2 * 16 * 64 * 8];  // 32 KB: [plane][ct][lane][8]
    __shared__ int hist[KK];
    if (blockIdx.x == 0 && threadIdx.x == 0) *shiftsq = 0.0f;
    hist[threadIdx.x] = 0;

    const int wave = threadIdx.x >> 6;
    const int lane = threadIdx.x & 63;
    const int l4 = lane & 15, g = lane >> 4;
    const int g16 = blockIdx.x * 8 + wave * 2;

    f32x4 acc[2][16];
#pragma unroll
    for (int pg = 0; pg < 2; pg++)
#pragma unroll
        for (int ct = 0; ct < 16; ct++) acc[pg][ct] = (f32x4){0.f, 0.f, 0.f, 0.f};

    char* lds0 = (char*)Bls;
#pragma unroll 1
    for (int ks = 0; ks < 4; ks++) {
        // A frags for THIS slice only (16 VGPRs) — issued before the barrier
        // so global-load latency overlaps the staging drain.
        const size_t a0 = ((size_t)(g16 * 4 + ks) * 64 + lane) * 8;
        const size_t a1 = ((size_t)((g16 + 1) * 4 + ks) * 64 + lane) * 8;
        half8 ah0 = *(const half8*)(Xh + a0);
        half8 al0 = *(const half8*)(Xl + a0);
        half8 ah1 = *(const half8*)(Xh + a1);
        half8 al1 = *(const half8*)(Xl + a1);

        __syncthreads();  // previous slice fully consumed before overwrite
        // Stage 16 KB Ch-slice + 16 KB Cl-slice: per wave per j, 64 lanes x 16B.
#pragma unroll
        for (int j = 0; j < 4; j++) {
            const int slot = j * 256 + wave * 64;  // 16B units within plane
            async_copy16(Ch + (size_t)ks * 8192 + (size_t)(slot + lane) * 8,
                         lds0 + (size_t)slot * 16);
            async_copy16(Cl + (size_t)ks * 8192 + (size_t)(slot + lane) * 8,
                         lds0 + 16384 + (size_t)slot * 16);
        }
        __syncthreads();  // vmcnt(0) drain -> staged B (and A regs) ready

#pragma unroll
        for (int ct = 0; ct < 16; ct++) {
            half8 bh = *(const half8*)(lds0 + ct * 1024 + lane * 16);
            half8 bl = *(const half8*)(lds0 + 16384 + ct * 1024 + lane * 16);
            acc[0][ct] = __builtin_amdgcn_mfma_f32_16x16x32_f16(al0, bh, acc[0][ct], 0, 0, 0);
            acc[0][ct] = __builtin_amdgcn_mfma_f32_16x16x32_f16(ah0, bl, acc[0][ct], 0, 0, 0);
            acc[0][ct] = __builtin_amdgcn_mfma_f32_16x16x32_f16(ah0, bh, acc[0][ct], 0, 0, 0);
            acc[1][ct] = __builtin_amdgcn_mfma_f32_16x16x32_f16(al1, bh, acc[1][ct], 0, 0, 0);
            acc[1][ct] = __builtin_amdgcn_mfma_f32_16x16x32_f16(ah1, bl, acc[1][ct], 0, 0, 0);
            acc[1][ct] = __builtin_amdgcn_mfma_f32_16x16x32_f16(ah1, bh, acc[1][ct], 0, 0, 0);
        }
    }

    float cn[16];
#pragma unroll
    for (int ct = 0; ct < 16; ct++) cn[ct] = cnorm[ct * 16 + l4];

    // Packed argmin keys: (monotone(float) << 32) | cluster. NaN -> -inf so
    // NaN beats all finite values; low bits give np's first-index tie-break.
    unsigned long long best[2][4];
#pragma unroll
    for (int pg = 0; pg < 2; pg++)
#pragma unroll
        for (int r = 0; r < 4; r++) best[pg][r] = ~0ull;

#pragma unroll
    for (int pg = 0; pg < 2; pg++)
#pragma unroll
        for (int ct = 0; ct < 16; ct++)
#pragma unroll
            for (int r = 0; r < 4; r++) {
                float s = fmaf(-2.0f, acc[pg][ct][r], cn[ct]);
                if (__builtin_isnan(s)) s = -__builtin_inff();
                unsigned u = __float_as_uint(s);
                unsigned m = (u >> 31) ? ~u : (u ^ 0x80000000u);
                unsigned long long key =
                    ((unsigned long long)m << 32) | (unsigned)(ct * 16 + l4);
                if (key < best[pg][r]) best[pg][r] = key;
            }

    // reduce over the 16 cluster-column lanes (low 4 lane bits)
#pragma unroll
    for (int d = 1; d < 16; d <<= 1)
#pragma unroll
        for (int pg = 0; pg < 2; pg++)
#pragma unroll
            for (int r = 0; r < 4; r++) {
                unsigned long long o = __shfl_xor(best[pg][r], d, 64);
                if (o < best[pg][r]) best[pg][r] = o;
            }

    __syncthreads();  // hist zero visible (also orders vs staging barriers)
    if (l4 == 0) {
#pragma unroll
        for (int pg = 0; pg < 2; pg++)
#pragma unroll
            for (int r = 0; r < 4; r++) {
                int point = blockIdx.x * 128 + wave * 32 + pg * 16 + g * 4 + r;
                int lbl = (int)(best[pg][r] & 0x1ff);
                outlab[point] = (float)lbl;
                ilab[point] = lbl;
                atomicAdd(&hist[lbl], 1);
            }
    }
    __syncthreads();
    int h = hist[threadIdx.x];
    if (h) atomicAdd(&counts[threadIdx.x], h);
}

// Counting-sort scatter. Block = 512 points: LDS histogram, redundant prefix
// of global counts, ONE block-aggregated cursor reservation per cluster, then
// rank & write ordlab[pos] = p | (label<<17). Also zeroes sums for k_sum.
// grid: NP/512 = 256 blocks x 256 threads.
__global__ __launch_bounds__(256) void k_scatter(
    const int* __restrict__ ilab, const int* __restrict__ counts,
    int* __restrict__ cursor, int* __restrict__ ordlab,
    float* __restrict__ sums) {
    const int t = threadIdx.x;
    const int b = blockIdx.x;

    // zero sums slice: 256 blocks x 128 floats = KK*DD
    if (t < 128) sums[b * 128 + t] = 0.0f;

    __shared__ int hist[KK];
    __shared__ int pre[KK];
    __shared__ int gbase[KK];
    hist[t] = 0;
    int c = counts[t];
    pre[t] = c;
    __syncthreads();

    const int p0 = b * 512;
    const int la = ilab[p0 + t];
    const int lb = ilab[p0 + 256 + t];
    atomicAdd(&hist[la], 1);
    atomicAdd(&hist[lb], 1);

    // inclusive prefix of counts (Hillis-Steele)
#pragma unroll
    for (int d = 1; d < KK; d <<= 1) {
        int v = (t >= d) ? pre[t - d] : 0;
        __syncthreads();
        pre[t] += v;
        __syncthreads();
    }
    // after these syncs all hist atomics are complete
    int h = hist[t];
    int gb = (pre[t] - c) + (h ? atomicAdd(&cursor[t], h) : 0);
    gbase[t] = gb;
    __syncthreads();
    hist[t] = 0;  // reuse as intra-block rank cursor
    __syncthreads();

    int ra = atomicAdd(&hist[la], 1);
    ordlab[gbase[la] + ra] = (p0 + t) | (la << 17);
    int rb = atomicAdd(&hist[lb], 1);
    ordlab[gbase[lb] + rb] = (p0 + 256 + t) | (lb << 17);
}

// Streaming segmented sum over the cluster-sorted position list.
// Position-balanced (immune to cluster-size skew). Thread = (dim d, parity h);
// U-deep double-buffered row gathers; register accumulator flushed on label
// change (wave-uniform branch) via coalesced global atomicAdd — few per block.
// grid: NP/POSB = 512 blocks x 256 threads.
__global__ __launch_bounds__(256) void k_sum(
    const float* __restrict__ X, const int* __restrict__ ordlab,
    float* __restrict__ sums) {
    const int t = threadIdx.x;
    const int d = t & 127, h = t >> 7;

    __shared__ int sol[POSB];
    sol[t] = ordlab[blockIdx.x * POSB + t];
    __syncthreads();

    const int PP = POSB / 2;  // positions per parity
    float xv[UPIPE], xn[UPIPE];
#pragma unroll
    for (int u = 0; u < UPIPE; u++)
        xv[u] = X[(size_t)(sol[2 * u + h] & 0x1ffff) * DD + d];

    float acc = 0.0f;
    int cur = sol[h] >> 17;

    for (int jb = 0; jb < PP; jb += UPIPE) {
        // issue next batch's gathers (tail clamped to a harmless valid index)
#pragma unroll
        for (int u = 0; u < UPIPE; u++) {
            int nj = jb + u + UPIPE;
            int o = sol[2 * (nj < PP ? nj : PP - 1) + h];
            xn[u] = X[(size_t)(o & 0x1ffff) * DD + d];
        }
        // consume current batch
#pragma unroll
        for (int u = 0; u < UPIPE; u++) {
            int l = sol[2 * (jb + u) + h] >> 17;
            if (l != cur) {
                atomicAdd(&sums[cur * DD + d], acc);
                acc = 0.0f;
                cur = l;
            }
            acc += xv[u];
        }
#pragma unroll
        for (int u = 0; u < UPIPE; u++) xv[u] = xn[u];
    }
    atomicAdd(&sums[cur * DD + d], acc);
}

// newC = sums/counts (0/0 -> NaN, matching jnp); shift^2 block-reduced,
// one atomic per block.  grid: KK*DD/256 x 256
__global__ void k_reduce(const float* __restrict__ sums, const int* __restrict__ counts,
                         const float* __restrict__ C, float* __restrict__ newC,
                         float* __restrict__ shiftsq) {
    const int g = blockIdx.x * 256 + threadIdx.x;
    const int k = g >> 7;
    const int t = threadIdx.x;

    float nc = sums[g] / (float)counts[k];
    newC[g] = nc;
    float diff = nc - C[g];

    __shared__ float red[256];
    red[t] = diff * diff;
    __syncthreads();
    for (int st = 128; st > 0; st >>= 1) {
        if (t < st) red[t] += red[t + st];
        __syncthreads();
    }
    if (t == 0) atomicAdd(shiftsq, red[0]);
}

// Fused convergence check + centroid update + next-iter prep (cnorm + hi/lo
// planes) + zero counts/cursor. NaN shiftsq -> not converged (jnp match).
// Benign done race: all blocks compute the same nd.  grid: KK/2 x 256.
__global__ void k_upprep(const float* __restrict__ newC, float* __restrict__ C,
                         const float* __restrict__ shiftsq, int* __restrict__ done,
                         float* __restrict__ cnorm, _Float16* __restrict__ Ch,
                         _Float16* __restrict__ Cl, int* __restrict__ counts,
                         int* __restrict__ cursor) {
    const int t = threadIdx.x;
    const int k = blockIdx.x * 2 + (t >> 7);
    const int d = t & 127;
    float ss = *shiftsq;
    int nd = (*done != 0) || (ss < TOLSQ);
    float v = nd ? C[k * DD + d] : newC[k * DD + d];
    C[k * DD + d] = v;
    if (blockIdx.x == 0 && t == 0 && nd) *done = 1;
    if (d == 0) {
        counts[k] = 0;
        cursor[k] = 0;
    }

    _Float16 hi = (_Float16)v;
    int ct = k >> 4, l4 = k & 15, ks = d >> 5, q = (d >> 3) & 3, j = d & 7;
    size_t dst = ((size_t)(ks * 16 + ct) * 64 + (q * 16 + l4)) * 8 + j;
    Ch[dst] = hi;
    Cl[dst] = (_Float16)(v - (float)hi);

    __shared__ float red[256];
    red[t] = v * v;
    __syncthreads();
    for (int s = 64; s > 0; s >>= 1) {
        if ((t & 127) < s) red[t] += red[t + s];
        __syncthreads();
    }
    if (d == 0) cnorm[k] = red[t];
}

__global__ void k_final(const float* __restrict__ C, float* __restrict__ out) {
    int i = blockIdx.x * 256 + threadIdx.x;
    out[i] = C[i];
}

extern "C" void kernel_launch(void* const* d_in, const int* in_sizes, int n_in,
                              void* d_out, int out_size, void* d_ws, size_t ws_size,
                              hipStream_t stream) {
    const float* X = (const float*)d_in[0];
    const int* idx = (const int*)d_in[1];
    float* out = (float*)d_out;
    Ws* w = (Ws*)d_ws;

    k_init<<<KK, DD, 0, stream>>>(X, idx, w->C, &w->done);
    k_split<<<(int)((size_t)NP * DD / 8 / 256), 256, 0, stream>>>(X, w->Xsh, w->Xsl);
    k_prep0<<<KK, DD, 0, stream>>>(w->C, w->cnorm, w->Csh, w->Csl, w->counts, w->cursor);

    for (int it = 0; it < MAXIT; it++) {
        k_assign<<<NP / 128, 256, 0, stream>>>(w->Xsh, w->Xsl, w->Csh, w->Csl,
                                               w->cnorm, out, w->ilab, w->counts,
                                               &w->shiftsq);
        k_scatter<<<NP / 512, 256, 0, stream>>>(w->ilab, w->counts, w->cursor,
                                                w->ordlab, w->sums);
        k_sum<<<NP / POSB, 256, 0, stream>>>(X, w->ordlab, w->sums);
        k_reduce<<<KK * DD / 256, 256, 0, stream>>>(w->sums, w->counts, w->C,
                                                    w->newC, &w->shiftsq);
        k_upprep<<<KK / 2, 256, 0, stream>>>(w->newC, w->C, &w->shiftsq, &w->done,
                                             w->cnorm, w->Csh, w->Csl, w->counts,
                                             w->cursor);
    }

    k_final<<<KK * DD / 256, 256, 0, stream>>>(w->C, out + NP);
}

// Round 10
// 711.659 us; speedup vs baseline: 4.6707x; 1.0152x over previous
//
#include <hip/hip_runtime.h>

#define NP 131072   // points (= 2^17, label packs above bit 17)
#define DD 128      // dims (GEMM K)
#define KK 256      // clusters (GEMM N)
#define MAXIT 8
#define TOLSQ (1e-4f * 1e-4f)
#define POSB 256    // positions per k_sum block
#define UPIPE 8     // gather pipeline depth

typedef _Float16 half8 __attribute__((ext_vector_type(8)));
typedef float f32x4 __attribute__((ext_vector_type(4)));

// Async 16B global -> LDS DMA. ldsptr must be the WAVE-UNIFORM base; HW
// writes base + lane*16 (m97/m104 semantics). Our layouts are exactly
// lane-contiguous in fragment order.
__device__ __forceinline__ void async_copy16(const void* g, void* l) {
    __builtin_amdgcn_global_load_lds(
        (const __attribute__((address_space(1))) void*)g,
        (__attribute__((address_space(3))) void*)l, 16, 0, 0);
}

// ws re-poisoned 0xAA before every timed call — every field below is written
// before it is read on every kernel_launch.
struct Ws {
    float C[KK * DD];
    float newC[KK * DD];
    float cnorm[KK];
    float sums[KK * DD];       // per-cluster coordinate sums (atomic-flushed)
    float shiftsq;
    int done;
    int ilab[NP];              // labels
    int counts[KK];            // per-cluster sizes (exact, int)
    int cursor[KK];            // global reservation cursors (zeroed per iter)
    int ordlab[NP];            // cluster-sorted: point | (label<<17)
    // fp16 hi/lo planes, pre-swizzled into MFMA fragment order (16B aligned)
    alignas(16) _Float16 Csh[KK * DD];
    alignas(16) _Float16 Csl[KK * DD];
    alignas(16) _Float16 Xsh[(size_t)NP * DD];
    alignas(16) _Float16 Xsl[(size_t)NP * DD];
};

// C0 = X[init_idx]; zero done flag.  grid: KK x DD
__global__ void k_init(const float* __restrict__ X, const int* __restrict__ idx,
                       float* __restrict__ C, int* __restrict__ done) {
    int k = blockIdx.x, d = threadIdx.x;
    C[k * DD + d] = X[(size_t)idx[k] * DD + d];
    if (k == 0 && d == 0) *done = 0;
}

// Once per call: split X into fp16 hi/lo planes in A-fragment order.
// A-frag (16x16x32 f16): lane L of the wave owning 16-point group g16 at
// k-step ks holds X[g16*16 + (L&15)][ks*32 + (L>>4)*8 + j], j=0..7.
// Flat: Xs[(((g16*4)+ks)*64 + L)*8 + j].  grid: NP*DD/8/256 = 8192 blocks.
__global__ void k_split(const float* __restrict__ X, _Float16* __restrict__ Xh,
                        _Float16* __restrict__ Xl) {
    size_t idx = (size_t)blockIdx.x * 256 + threadIdx.x;  // one per 8 elems
    int lane = idx & 63;
    size_t g16k = idx >> 6;
    size_t point = (g16k >> 2) * 16 + (lane & 15);
    int dim0 = (int)(g16k & 3) * 32 + (lane >> 4) * 8;
    const f32x4* s4 = (const f32x4*)(X + point * DD + dim0);
    f32x4 a = s4[0], b = s4[1];
    half8 h, l;
#pragma unroll
    for (int j = 0; j < 4; j++) {
        _Float16 hi = (_Float16)a[j];
        h[j] = hi; l[j] = (_Float16)(a[j] - (float)hi);
    }
#pragma unroll
    for (int j = 0; j < 4; j++) {
        _Float16 hi = (_Float16)b[j];
        h[4 + j] = hi; l[4 + j] = (_Float16)(b[j] - (float)hi);
    }
    *(half8*)(Xh + idx * 8) = h;
    *(half8*)(Xl + idx * 8) = l;
}

// Initial prep: cnorm + hi/lo B-fragment planes for C0; zero counts/cursor.
// B-frag: lane L at (ks, cluster-tile ct) holds C[ct*16+(L&15)][ks*32+(L>>4)*8+j]
// -> flat ((ks*16+ct)*64 + L)*8 + j.  grid: KK x DD
__global__ void k_prep0(const float* __restrict__ C, float* __restrict__ cnorm,
                        _Float16* __restrict__ Ch, _Float16* __restrict__ Cl,
                        int* __restrict__ counts, int* __restrict__ cursor) {
    int k = blockIdx.x, d = threadIdx.x;
    float v = C[k * DD + d];
    _Float16 hi = (_Float16)v;
    int ct = k >> 4, l4 = k & 15, ks = d >> 5, q = (d >> 3) & 3, j = d & 7;
    size_t dst = ((size_t)(ks * 16 + ct) * 64 + (q * 16 + l4)) * 8 + j;
    Ch[dst] = hi;
    Cl[dst] = (_Float16)(v - (float)hi);
    __shared__ float red[DD];
    red[d] = v * v;
    __syncthreads();
    for (int s = DD / 2; s > 0; s >>= 1) {
        if (d < s) red[d] += red[d + s];
        __syncthreads();
    }
    if (d == 0) {
        cnorm[k] = red[0];
        counts[k] = 0;
        cursor[k] = 0;
    }
}

// MFMA assignment, DOUBLE-BUFFERED LDS-staged B. stage(ks+1) is issued BEFORE
// compute(ks); the single end-of-slice barrier then drains a DMA that has had
// the whole compute phase (~2K cyc) to complete — no exposed L2 round-trip
// (R9's single-buffer loop exposed the full drain 4x/block). The barrier also
// guarantees bufCur is fully consumed before iter ks+2 overwrites it.
// Wave = 32 points x 256 clusters; fp16 hi/lo 3-term split, fp32 acc.
// LDS: 2 x 32 KB buffers + hist = 65.5 KB -> 2 blocks/CU. grid: NP/128 x 256.
__global__ __launch_bounds__(256, 2) void k_assign(
    const _Float16* __restrict__ Xh, const _Float16* __restrict__ Xl,
    const _Float16* __restrict__ Ch, const _Float16* __restrict__ Cl,
    const float* __restrict__ cnorm, float* __restrict__ outlab,
    int* __restrict__ ilab, int* __restrict__ counts,
    float* __restrict__ shiftsq) {
    __shared__ __align__(16) _Float16 Bls[2 * 2 * 16 * 64 * 8];  // 2 bufs x 32 KB
    __shared__ int hist[KK];
    if (blockIdx.x == 0 && threadIdx.x == 0) *shiftsq = 0.0f;
    hist[threadIdx.x] = 0;

    const int wave = threadIdx.x >> 6;
    const int lane = threadIdx.x & 63;
    const int l4 = lane & 15, g = lane >> 4;
    const int g16 = blockIdx.x * 8 + wave * 2;
    char* const lds = (char*)Bls;

    // Stage one 32 KB slice (Ch half + Cl half) into buffer `buf`.
    auto stage = [&](int ks, int buf) {
        char* dst = lds + buf * 32768;
#pragma unroll
        for (int j = 0; j < 4; j++) {
            const int slot = j * 256 + wave * 64;  // 16B units within plane
            async_copy16(Ch + (size_t)ks * 8192 + (size_t)(slot + lane) * 8,
                         dst + (size_t)slot * 16);
            async_copy16(Cl + (size_t)ks * 8192 + (size_t)(slot + lane) * 8,
                         dst + 16384 + (size_t)slot * 16);
        }
    };

    f32x4 acc[2][16];
#pragma unroll
    for (int pg = 0; pg < 2; pg++)
#pragma unroll
        for (int ct = 0; ct < 16; ct++) acc[pg][ct] = (f32x4){0.f, 0.f, 0.f, 0.f};

    stage(0, 0);
    __syncthreads();  // prologue drain (only exposed drain in the kernel)

#pragma unroll 1
    for (int ks = 0; ks < 4; ks++) {
        if (ks < 3) stage(ks + 1, (ks + 1) & 1);  // fire-and-forget into other buf

        // A frags for THIS slice (16 VGPRs); latency hidden under ds_reads.
        const size_t a0 = ((size_t)(g16 * 4 + ks) * 64 + lane) * 8;
        const size_t a1 = ((size_t)((g16 + 1) * 4 + ks) * 64 + lane) * 8;
        half8 ah0 = *(const half8*)(Xh + a0);
        half8 al0 = *(const half8*)(Xl + a0);
        half8 ah1 = *(const half8*)(Xh + a1);
        half8 al1 = *(const half8*)(Xl + a1);

        char* cur = lds + (ks & 1) * 32768;
#pragma unroll
        for (int ct = 0; ct < 16; ct++) {
            half8 bh = *(const half8*)(cur + ct * 1024 + lane * 16);
            half8 bl = *(const half8*)(cur + 16384 + ct * 1024 + lane * 16);
            acc[0][ct] = __builtin_amdgcn_mfma_f32_16x16x32_f16(al0, bh, acc[0][ct], 0, 0, 0);
            acc[0][ct] = __builtin_amdgcn_mfma_f32_16x16x32_f16(ah0, bl, acc[0][ct], 0, 0, 0);
            acc[0][ct] = __builtin_amdgcn_mfma_f32_16x16x32_f16(ah0, bh, acc[0][ct], 0, 0, 0);
            acc[1][ct] = __builtin_amdgcn_mfma_f32_16x16x32_f16(al1, bh, acc[1][ct], 0, 0, 0);
            acc[1][ct] = __builtin_amdgcn_mfma_f32_16x16x32_f16(ah1, bl, acc[1][ct], 0, 0, 0);
            acc[1][ct] = __builtin_amdgcn_mfma_f32_16x16x32_f16(ah1, bh, acc[1][ct], 0, 0, 0);
        }
        __syncthreads();  // drains DMA(ks+1) AFTER compute covered its latency
    }

    float cn[16];
#pragma unroll
    for (int ct = 0; ct < 16; ct++) cn[ct] = cnorm[ct * 16 + l4];

    // Packed argmin keys: (monotone(float) << 32) | cluster. NaN -> -inf so
    // NaN beats all finite values; low bits give np's first-index tie-break.
    unsigned long long best[2][4];
#pragma unroll
    for (int pg = 0; pg < 2; pg++)
#pragma unroll
        for (int r = 0; r < 4; r++) best[pg][r] = ~0ull;

#pragma unroll
    for (int pg = 0; pg < 2; pg++)
#pragma unroll
        for (int ct = 0; ct < 16; ct++)
#pragma unroll
            for (int r = 0; r < 4; r++) {
                float s = fmaf(-2.0f, acc[pg][ct][r], cn[ct]);
                if (__builtin_isnan(s)) s = -__builtin_inff();
                unsigned u = __float_as_uint(s);
                unsigned m = (u >> 31) ? ~u : (u ^ 0x80000000u);
                unsigned long long key =
                    ((unsigned long long)m << 32) | (unsigned)(ct * 16 + l4);
                if (key < best[pg][r]) best[pg][r] = key;
            }

    // reduce over the 16 cluster-column lanes (low 4 lane bits)
#pragma unroll
    for (int d = 1; d < 16; d <<= 1)
#pragma unroll
        for (int pg = 0; pg < 2; pg++)
#pragma unroll
            for (int r = 0; r < 4; r++) {
                unsigned long long o = __shfl_xor(best[pg][r], d, 64);
                if (o < best[pg][r]) best[pg][r] = o;
            }

    __syncthreads();  // hist zero visible (ordered by loop barriers too)
    if (l4 == 0) {
#pragma unroll
        for (int pg = 0; pg < 2; pg++)
#pragma unroll
            for (int r = 0; r < 4; r++) {
                int point = blockIdx.x * 128 + wave * 32 + pg * 16 + g * 4 + r;
                int lbl = (int)(best[pg][r] & 0x1ff);
                outlab[point] = (float)lbl;
                ilab[point] = lbl;
                atomicAdd(&hist[lbl], 1);
            }
    }
    __syncthreads();
    int h = hist[threadIdx.x];
    if (h) atomicAdd(&counts[threadIdx.x], h);
}

// Counting-sort scatter. Block = 512 points: LDS histogram, redundant prefix
// of global counts, ONE block-aggregated cursor reservation per cluster, then
// rank & write ordlab[pos] = p | (label<<17). Also zeroes sums for k_sum.
// grid: NP/512 = 256 blocks x 256 threads.
__global__ __launch_bounds__(256) void k_scatter(
    const int* __restrict__ ilab, const int* __restrict__ counts,
    int* __restrict__ cursor, int* __restrict__ ordlab,
    float* __restrict__ sums) {
    const int t = threadIdx.x;
    const int b = blockIdx.x;

    // zero sums slice: 256 blocks x 128 floats = KK*DD
    if (t < 128) sums[b * 128 + t] = 0.0f;

    __shared__ int hist[KK];
    __shared__ int pre[KK];
    __shared__ int gbase[KK];
    hist[t] = 0;
    int c = counts[t];
    pre[t] = c;
    __syncthreads();

    const int p0 = b * 512;
    const int la = ilab[p0 + t];
    const int lb = ilab[p0 + 256 + t];
    atomicAdd(&hist[la], 1);
    atomicAdd(&hist[lb], 1);

    // inclusive prefix of counts (Hillis-Steele)
#pragma unroll
    for (int d = 1; d < KK; d <<= 1) {
        int v = (t >= d) ? pre[t - d] : 0;
        __syncthreads();
        pre[t] += v;
        __syncthreads();
    }
    // after these syncs all hist atomics are complete
    int h = hist[t];
    int gb = (pre[t] - c) + (h ? atomicAdd(&cursor[t], h) : 0);
    gbase[t] = gb;
    __syncthreads();
    hist[t] = 0;  // reuse as intra-block rank cursor
    __syncthreads();

    int ra = atomicAdd(&hist[la], 1);
    ordlab[gbase[la] + ra] = (p0 + t) | (la << 17);
    int rb = atomicAdd(&hist[lb], 1);
    ordlab[gbase[lb] + rb] = (p0 + 256 + t) | (lb << 17);
}

// Streaming segmented sum over the cluster-sorted position list.
// Position-balanced (immune to cluster-size skew). Thread = (dim d, parity h);
// U-deep double-buffered row gathers; register accumulator flushed on label
// change (wave-uniform branch) via coalesced global atomicAdd — few per block.
// grid: NP/POSB = 512 blocks x 256 threads.
__global__ __launch_bounds__(256) void k_sum(
    const float* __restrict__ X, const int* __restrict__ ordlab,
    float* __restrict__ sums) {
    const int t = threadIdx.x;
    const int d = t & 127, h = t >> 7;

    __shared__ int sol[POSB];
    sol[t] = ordlab[blockIdx.x * POSB + t];
    __syncthreads();

    const int PP = POSB / 2;  // positions per parity
    float xv[UPIPE], xn[UPIPE];
#pragma unroll
    for (int u = 0; u < UPIPE; u++)
        xv[u] = X[(size_t)(sol[2 * u + h] & 0x1ffff) * DD + d];

    float acc = 0.0f;
    int cur = sol[h] >> 17;

    for (int jb = 0; jb < PP; jb += UPIPE) {
        // issue next batch's gathers (tail clamped to a harmless valid index)
#pragma unroll
        for (int u = 0; u < UPIPE; u++) {
            int nj = jb + u + UPIPE;
            int o = sol[2 * (nj < PP ? nj : PP - 1) + h];
            xn[u] = X[(size_t)(o & 0x1ffff) * DD + d];
        }
        // consume current batch
#pragma unroll
        for (int u = 0; u < UPIPE; u++) {
            int l = sol[2 * (jb + u) + h] >> 17;
            if (l != cur) {
                atomicAdd(&sums[cur * DD + d], acc);
                acc = 0.0f;
                cur = l;
            }
            acc += xv[u];
        }
#pragma unroll
        for (int u = 0; u < UPIPE; u++) xv[u] = xn[u];
    }
    atomicAdd(&sums[cur * DD + d], acc);
}

// newC = sums/counts (0/0 -> NaN, matching jnp); shift^2 block-reduced,
// one atomic per block.  grid: KK*DD/256 x 256
__global__ void k_reduce(const float* __restrict__ sums, const int* __restrict__ counts,
                         const float* __restrict__ C, float* __restrict__ newC,
                         float* __restrict__ shiftsq) {
    const int g = blockIdx.x * 256 + threadIdx.x;
    const int k = g >> 7;
    const int t = threadIdx.x;

    float nc = sums[g] / (float)counts[k];
    newC[g] = nc;
    float diff = nc - C[g];

    __shared__ float red[256];
    red[t] = diff * diff;
    __syncthreads();
    for (int st = 128; st > 0; st >>= 1) {
        if (t < st) red[t] += red[t + st];
        __syncthreads();
    }
    if (t == 0) atomicAdd(shiftsq, red[0]);
}

// Fused convergence check + centroid update + next-iter prep (cnorm + hi/lo
// planes) + zero counts/cursor. NaN shiftsq -> not converged (jnp match).
// Benign done race: all blocks compute the same nd.  grid: KK/2 x 256.
__global__ void k_upprep(const float* __restrict__ newC, float* __restrict__ C,
                         const float* __restrict__ shiftsq, int* __restrict__ done,
                         float* __restrict__ cnorm, _Float16* __restrict__ Ch,
                         _Float16* __restrict__ Cl, int* __restrict__ counts,
                         int* __restrict__ cursor) {
    const int t = threadIdx.x;
    const int k = blockIdx.x * 2 + (t >> 7);
    const int d = t & 127;
    float ss = *shiftsq;
    int nd = (*done != 0) || (ss < TOLSQ);
    float v = nd ? C[k * DD + d] : newC[k * DD + d];
    C[k * DD + d] = v;
    if (blockIdx.x == 0 && t == 0 && nd) *done = 1;
    if (d == 0) {
        counts[k] = 0;
        cursor[k] = 0;
    }

    _Float16 hi = (_Float16)v;
    int ct = k >> 4, l4 = k & 15, ks = d >> 5, q = (d >> 3) & 3, j = d & 7;
    size_t dst = ((size_t)(ks * 16 + ct) * 64 + (q * 16 + l4)) * 8 + j;
    Ch[dst] = hi;
    Cl[dst] = (_Float16)(v - (float)hi);

    __shared__ float red[256];
    red[t] = v * v;
    __syncthreads();
    for (int s = 64; s > 0; s >>= 1) {
        if ((t & 127) < s) red[t] += red[t + s];
        __syncthreads();
    }
    if (d == 0) cnorm[k] = red[t];
}

__global__ void k_final(const float* __restrict__ C, float* __restrict__ out) {
    int i = blockIdx.x * 256 + threadIdx.x;
    out[i] = C[i];
}

extern "C" void kernel_launch(void* const* d_in, const int* in_sizes, int n_in,
                              void* d_out, int out_size, void* d_ws, size_t ws_size,
                              hipStream_t stream) {
    const float* X = (const float*)d_in[0];
    const int* idx = (const int*)d_in[1];
    float* out = (float*)d_out;
    Ws* w = (Ws*)d_ws;

    k_init<<<KK, DD, 0, stream>>>(X, idx, w->C, &w->done);
    k_split<<<(int)((size_t)NP * DD / 8 / 256), 256, 0, stream>>>(X, w->Xsh, w->Xsl);
    k_prep0<<<KK, DD, 0, stream>>>(w->C, w->cnorm, w->Csh, w->Csl, w->counts, w->cursor);

    for (int it = 0; it < MAXIT; it++) {
        k_assign<<<NP / 128, 256, 0, stream>>>(w->Xsh, w->Xsl, w->Csh, w->Csl,
                                               w->cnorm, out, w->ilab, w->counts,
                                               &w->shiftsq);
        k_scatter<<<NP / 512, 256, 0, stream>>>(w->ilab, w->counts, w->cursor,
                                                w->ordlab, w->sums);
        k_sum<<<NP / POSB, 256, 0, stream>>>(X, w->ordlab, w->sums);
        k_reduce<<<KK * DD / 256, 256, 0, stream>>>(w->sums, w->counts, w->C,
                                                    w->newC, &w->shiftsq);
        k_upprep<<<KK / 2, 256, 0, stream>>>(w->newC, w->C, &w->shiftsq, &w->done,
                                             w->cnorm, w->Csh, w->Csl, w->counts,
                                             w->cursor);
    }

    k_final<<<KK * DD / 256, 256, 0, stream>>>(w->C, out + NP);
}